// Round 9
// baseline (26.499 us; speedup 1.0000x reference)
//
#include <hip/hip_runtime.h>
#include <hip/hip_bf16.h>
#include <math.h>

// Problem constants (fixed by setup_inputs)
constexpr int B_ = 16, S_ = 512, T_ = 4096, E_ = 256;

typedef __attribute__((ext_vector_type(8))) short short8;
typedef __attribute__((ext_vector_type(4))) float f32x4;

// Workspace layout (bytes)
constexpr size_t FLAGS_OFF = 0;             // 32 ints
constexpr size_t WT_OFF    = 4096;          // 256x256 bf16 W^T = 128KB

// -ln(10000)/256
#define NEGC (-0.035977892f)

__device__ __forceinline__ unsigned pk_bf16(float a, float b) {
    __hip_bfloat162 h = __float22bfloat162_rn(make_float2(a, b));
    return *(unsigned*)&h;
}
__device__ __forceinline__ short bf16s(float x) {
    unsigned u = __float_as_uint(x);
    u += 0x7FFFu + ((u >> 16) & 1u);
    return (short)(u >> 16);
}

// ---------------------------------------------------------------------------
// Prep: [0,32) aligner-recurrence validation (8 ids/thread, int4) -> flags;
//       [32,48) W^T -> bf16 wt.  (R5-proven, unchanged)
__global__ __launch_bounds__(256) void k_prep(
    const int* __restrict__ align, const int* __restrict__ text,
    const float* __restrict__ W,
    int* __restrict__ flags, short* __restrict__ wt)
{
    const int bid = blockIdx.x, tid = threadIdx.x;
    if (bid < 32) {
        __shared__ int f;
        if (tid == 0) f = 0;
        __syncthreads();
        const int base = (bid * 256 + tid) * 8;
        const int4 a0 = *(const int4*)(align + base);
        const int4 a1 = *(const int4*)(align + base + 4);
        const int av[8] = {a0.x, a0.y, a0.z, a0.w, a1.x, a1.y, a1.z, a1.w};
        int bad = 0;
#pragma unroll
        for (int m = 0; m < 8; ++m) {
            const int id = base + m;
            const int t = id & (T_ - 1), b = id >> 12;
            if (t > 0) {
                const int prev = (t - 1) >> 3;
                const int expct = (av[m] == text[b * S_ + prev]) ? prev : min(prev + 1, S_ - 1);
                if ((t >> 3) != expct) bad = 1;
            }
        }
        if (bad) f = 1;                  // benign race: all writers store 1
        __syncthreads();
        if (tid == 0) flags[bid] = f;
    } else {
        const int kb = (bid - 32) * 16;
        short8 v0, v1;
#pragma unroll
        for (int j = 0; j < 8; ++j) v0[j] = bf16s(W[(kb + j) * E_ + tid]);
#pragma unroll
        for (int j = 0; j < 8; ++j) v1[j] = bf16s(W[(kb + 8 + j) * E_ + tid]);
        *(short8*)(wt + tid * E_ + kb)     = v0;
        *(short8*)(wt + tid * E_ + kb + 8) = v1;
    }
}

// ---------------------------------------------------------------------------
// Fused GEMM (R8 structure, A/B change: PLAIN stores instead of nontemporal).
// Block = 4 phones x 16 batches x 32 N-cols; grid (128, 8); 3 blocks/CU.
__global__ __launch_bounds__(256, 3) void k_fused(
    const float* __restrict__ enc, const short* __restrict__ wt,
    const float* __restrict__ bpos,
    const float* __restrict__ pitch, const int* __restrict__ beats,
    const float* __restrict__ wpitch, const float* __restrict__ bpitch,
    const float* __restrict__ embb,
    const float* __restrict__ W, const int* __restrict__ align,
    const int* __restrict__ text, const int* __restrict__ flags,
    float* __restrict__ out)
{
    __shared__ __align__(16) short As[64 * 256];   // 32KB: PE rows 0-31 -> enc 0-63 -> ew f32[64][36]
    __shared__ __align__(16) short Bs[32 * 256];   // 16KB  W^T slice [n][k]
    __shared__ float pl[4 * 256];                  // 4KB   PEW patches [tq*2+nq][16][16]

    const int tid = threadIdx.x;
    const int i0 = blockIdx.x * 4;                 // phone base
    const int n0 = blockIdx.y * 32;
    const int t0base = i0 * 8;

    // ---- fallback flag (never set for this data) ----
    const bool fb = __any(flags[tid & 31] != 0);
    if (fb) {
        // exact fp32 slow path (never taken). idxl aliases As.
        int (*idxl)[32] = (int(*)[32])As;
        if (tid < 16) {
            int i = 0;
            const int b = tid;
            if (i0 == 0) idxl[b][0] = 0;
            for (int t = 1; t < t0base + 32; ++t) {
                if (align[b * T_ + t] != text[b * S_ + i]) i = min(i + 1, S_ - 1);
                if (t >= t0base) idxl[b][t - t0base] = i;
            }
        }
        __syncthreads();
#pragma unroll
        for (int rr = 0; rr < 2; ++rr) {
            const int r = tid * 2 + rr;            // 0..511 = 16b x 32t
            const int bq = r >> 5, tt = r & 31;
            const int t = t0base + tt;
            const int i = idxl[bq][tt];
            const float* erow = enc + (size_t)(bq * S_ + i) * E_;
            const float p = pitch[(size_t)bq * T_ + t];
            const int bt = beats[(size_t)bq * T_ + t];
            for (int cc = 0; cc < 32; ++cc) {
                const int col = n0 + cc;
                float acc = 0.f;
                for (int k2 = 0; k2 < 128; ++k2) {
                    const float dd = __expf((float)(2 * k2) * NEGC);
                    float s, c;
                    __sincosf((float)t * dd, &s, &c);
                    acc += (erow[2 * k2] + s) * W[(2 * k2) * E_ + col]
                         + (erow[2 * k2 + 1] + c) * W[(2 * k2 + 1) * E_ + col];
                }
                out[((size_t)bq * T_ + t) * E_ + col] =
                    erow[col] + acc + bpos[col] + p * wpitch[col] + bpitch[col]
                    + (bt ? embb[E_ + col] : embb[col]);
            }
        }
        return;
    }

    // ---- stage Bs: wt rows n0..n0+32 (vector, swizzled) ----
    {
        const int r = tid >> 3, c8 = tid & 7;
        const short* bp = wt + (size_t)(n0 + r) * E_;
#pragma unroll
        for (int jj = 0; jj < 4; ++jj) {
            const int seg = c8 + 8 * jj;
            short8 v = *(const short8*)(bp + seg * 8);
            *(short8*)&Bs[(r * 256 + seg * 8) ^ ((r & 7) << 3)] = v;
        }
    }
    // ---- stage As = PE rows 0..31 (on-the-fly sincos) ----
    {
        const int r = tid >> 3, c8 = tid & 7;
        const float tf = (float)(t0base + r);
#pragma unroll
        for (int jj = 0; jj < 4; ++jj) {
            const int seg = c8 * 4 + jj;
            union { short8 v; unsigned u[4]; } cv;
#pragma unroll
            for (int m = 0; m < 4; ++m) {
                const int j2 = seg * 4 + m;
                const float d = __expf((float)(2 * j2) * NEGC);
                float s, c;
                __sincosf(tf * d, &s, &c);
                cv.u[m] = pk_bf16(s, c);
            }
            *(short8*)&As[(r * 256 + seg * 8) ^ ((r & 7) << 3)] = cv.v;
        }
    }
    __syncthreads();

    const int wid = tid >> 6, lane = tid & 63;
    const int q = lane >> 4, c = lane & 15;

    // ---- phase 1 MFMA: 32x32 PEW slice, wave (tq, nq) = 16t x 16n ----
    {
        const int tq = wid >> 1, nqp = wid & 1;
        const int ar = tq * 16 + c;
        const int br = nqp * 16 + c;
        f32x4 p = {0.f, 0.f, 0.f, 0.f};
#pragma unroll
        for (int ks = 0; ks < 8; ++ks) {
            const int kidx = ks * 32 + q * 8;
            short8 a = *(const short8*)&As[(ar * 256 + kidx) ^ ((ar & 7) << 3)];
            short8 b = *(const short8*)&Bs[(br * 256 + kidx) ^ ((br & 7) << 3)];
            p = __builtin_amdgcn_mfma_f32_16x16x32_bf16(a, b, p, 0, 0, 0);
        }
#pragma unroll
        for (int rr = 0; rr < 4; ++rr)
            pl[(tq * 2 + nqp) * 256 + (q * 4 + rr) * 16 + c] = p[rr];
    }
    __syncthreads();   // As(PE) reads done; pl visible

    // ---- stage As = enc rows 0..63 (row r: b = r>>2, phone = i0 + (r&3)) ----
    {
        const int r = tid >> 2, c4 = tid & 3;
        const float* ap = enc + (size_t)((r >> 2) * S_ + i0 + (r & 3)) * E_;
#pragma unroll
        for (int jj = 0; jj < 8; ++jj) {
            const int seg = c4 + 4 * jj;
            float4 f0 = *(const float4*)(ap + seg * 8);
            float4 f1 = *(const float4*)(ap + seg * 8 + 4);
            union { short8 v; unsigned u[4]; } cv;
            cv.u[0] = pk_bf16(f0.x, f0.y);
            cv.u[1] = pk_bf16(f0.z, f0.w);
            cv.u[2] = pk_bf16(f1.x, f1.y);
            cv.u[3] = pk_bf16(f1.z, f1.w);
            *(short8*)&As[(r * 256 + seg * 8) ^ ((r & 7) << 3)] = cv.v;
        }
    }
    __syncthreads();

    // ---- phase 2 MFMA: wave (mq, nq) = 32 enc-rows x 16 cols, 16 MFMA ----
    const int mq = wid >> 1, nq = wid & 1;
    const int ra0 = mq * 32 + c, ra1 = ra0 + 16;
    const int rb = nq * 16 + c;
    f32x4 acc0 = {0.f, 0.f, 0.f, 0.f}, acc1 = {0.f, 0.f, 0.f, 0.f};
#pragma unroll
    for (int ks = 0; ks < 8; ++ks) {
        const int kidx = ks * 32 + q * 8;
        short8 a0 = *(const short8*)&As[(ra0 * 256 + kidx) ^ ((ra0 & 7) << 3)];
        short8 a1 = *(const short8*)&As[(ra1 * 256 + kidx) ^ ((ra1 & 7) << 3)];
        short8 b  = *(const short8*)&Bs[(rb * 256 + kidx) ^ ((rb & 7) << 3)];
        acc0 = __builtin_amdgcn_mfma_f32_16x16x32_bf16(a0, b, acc0, 0, 0, 0);
        acc1 = __builtin_amdgcn_mfma_f32_16x16x32_bf16(a1, b, acc1, 0, 0, 0);
    }

    // ---- pre-reads (pl stable since bar2; overlaps other waves' phase 2) ----
    const int c8q = tid & 7, rgrp = tid >> 3;      // tail: col-chunk, row-group
    const int j = rgrp & 3;                        // phone offset (same for both p)
    const int gc = n0 + 4 * c8q;
    f32x4 pv[8];
#pragma unroll
    for (int d = 0; d < 8; ++d) {
        const int tl = j * 8 + d;
        pv[d] = *(const f32x4*)&pl[((tl >> 4) * 2 + (c8q >> 2)) * 256
                                   + (tl & 15) * 16 + ((4 * c8q) & 15)];
    }
    const f32x4 wp4 = *(const f32x4*)(wpitch + gc);
    const f32x4 cst = *(const f32x4*)(bpitch + gc) + *(const f32x4*)(bpos + gc);
    const f32x4 be0 = *(const f32x4*)(embb + gc);
    const f32x4 be1 = *(const f32x4*)(embb + E_ + gc);
    __syncthreads();   // all As(enc) reads done -> reuse As as ew

    // ---- transpose acc through LDS (D: row = 4q+rr, col = c); stride 36 ----
    float* ew = (float*)As;                        // [64][36], 16B-aligned rows
#pragma unroll
    for (int rr = 0; rr < 4; ++rr) {
        ew[(mq * 32 + q * 4 + rr) * 36 + nq * 16 + c]      = acc0[rr];
        ew[(mq * 32 + 16 + q * 4 + rr) * 36 + nq * 16 + c] = acc1[rr];
    }
    __syncthreads();   // ew visible

    // ---- epilogue: lane = (rgrp, c8q); 2 row-passes x 8 frames; PLAIN stores ----
#pragma unroll
    for (int p = 0; p < 2; ++p) {
        const int row = rgrp + 32 * p;
        const int bq = row >> 2;
        const size_t prow = (size_t)bq * T_ + t0base + j * 8;
        const float4 pi0 = *(const float4*)(pitch + prow);
        const float4 pi1 = *(const float4*)(pitch + prow + 4);
        const int4  bt0 = *(const int4*)(beats + prow);
        const int4  bt1 = *(const int4*)(beats + prow + 4);
        const f32x4 e4  = *(const f32x4*)(enc + (size_t)(bq * S_ + i0 + j) * E_ + gc);
        const f32x4 ewv = *(const f32x4*)&ew[row * 36 + 4 * c8q];
        const f32x4 base = ewv + e4 + cst;
        const float pp[8] = {pi0.x, pi0.y, pi0.z, pi0.w, pi1.x, pi1.y, pi1.z, pi1.w};
        const int   bb[8] = {bt0.x, bt0.y, bt0.z, bt0.w, bt1.x, bt1.y, bt1.z, bt1.w};
#pragma unroll
        for (int d = 0; d < 8; ++d) {
            const f32x4 be = bb[d] ? be1 : be0;
            f32x4 o = base + pv[d] + pp[d] * wp4 + be;
            *(f32x4*)(out + (prow + d) * E_ + gc) = o;   // plain store (A/B vs nt)
        }
    }
}

// ---------------------------------------------------------------------------
extern "C" void kernel_launch(void* const* d_in, const int* in_sizes, int n_in,
                              void* d_out, int out_size, void* d_ws, size_t ws_size,
                              hipStream_t stream) {
    const float* enc    = (const float*)d_in[0];
    const int*   align  = (const int*)  d_in[1];
    const int*   text   = (const int*)  d_in[2];
    const float* pitch  = (const float*)d_in[3];
    const int*   beats  = (const int*)  d_in[4];
    const float* wpitch = (const float*)d_in[5];
    const float* bpitch = (const float*)d_in[6];
    const float* embb   = (const float*)d_in[7];
    const float* wpos   = (const float*)d_in[8];
    const float* bpos   = (const float*)d_in[9];
    float* out = (float*)d_out;

    char* ws = (char*)d_ws;
    int*   flags = (int*)  (ws + FLAGS_OFF);
    short* wt    = (short*)(ws + WT_OFF);

    hipLaunchKernelGGL(k_prep, dim3(48), dim3(256), 0, stream,
                       align, text, wpos, flags, wt);
    hipLaunchKernelGGL(k_fused, dim3(S_ / 4, 8), dim3(256), 0, stream,
                       enc, wt, bpos, pitch, beats, wpitch, bpitch, embb,
                       wpos, align, text, flags, out);
}

// Round 10
// 25.467 us; speedup vs baseline: 1.0405x; 1.0405x over previous
//
#include <hip/hip_runtime.h>
#include <hip/hip_bf16.h>
#include <math.h>

// Problem constants (fixed by setup_inputs)
constexpr int B_ = 16, S_ = 512, T_ = 4096, E_ = 256;

typedef __attribute__((ext_vector_type(8))) short short8;
typedef __attribute__((ext_vector_type(4))) float f32x4;

// Workspace layout (bytes)
constexpr size_t FLAGS_OFF = 0;             // 32 ints
constexpr size_t WT_OFF    = 4096;          // 256x256 bf16 W^T = 128KB

// -ln(10000)/256
#define NEGC (-0.035977892f)

__device__ __forceinline__ unsigned pk_bf16(float a, float b) {
    __hip_bfloat162 h = __float22bfloat162_rn(make_float2(a, b));
    return *(unsigned*)&h;
}
__device__ __forceinline__ short bf16s(float x) {
    unsigned u = __float_as_uint(x);
    u += 0x7FFFu + ((u >> 16) & 1u);
    return (short)(u >> 16);
}

// Raw barrier: LDS-visibility only — does NOT drain vmcnt, so global stores
// issued before it stay in flight (safe: no cross-wave reads of `out`).
// sched_barrier(0) prevents hipcc hoisting register-only ops across (rule #18).
__device__ __forceinline__ void rawbar() {
    asm volatile("s_waitcnt lgkmcnt(0)" ::: "memory");
    __builtin_amdgcn_s_barrier();
    __builtin_amdgcn_sched_barrier(0);
}

// ---------------------------------------------------------------------------
// Prep: [0,32) aligner-recurrence validation (8 ids/thread, int4) -> flags;
//       [32,48) W^T -> bf16 wt.  (R5-proven, unchanged)
__global__ __launch_bounds__(256) void k_prep(
    const int* __restrict__ align, const int* __restrict__ text,
    const float* __restrict__ W,
    int* __restrict__ flags, short* __restrict__ wt)
{
    const int bid = blockIdx.x, tid = threadIdx.x;
    if (bid < 32) {
        __shared__ int f;
        if (tid == 0) f = 0;
        __syncthreads();
        const int base = (bid * 256 + tid) * 8;
        const int4 a0 = *(const int4*)(align + base);
        const int4 a1 = *(const int4*)(align + base + 4);
        const int av[8] = {a0.x, a0.y, a0.z, a0.w, a1.x, a1.y, a1.z, a1.w};
        int bad = 0;
#pragma unroll
        for (int m = 0; m < 8; ++m) {
            const int id = base + m;
            const int t = id & (T_ - 1), b = id >> 12;
            if (t > 0) {
                const int prev = (t - 1) >> 3;
                const int expct = (av[m] == text[b * S_ + prev]) ? prev : min(prev + 1, S_ - 1);
                if ((t >> 3) != expct) bad = 1;
            }
        }
        if (bad) f = 1;                  // benign race: all writers store 1
        __syncthreads();
        if (tid == 0) flags[bid] = f;
    } else {
        const int kb = (bid - 32) * 16;
        short8 v0, v1;
#pragma unroll
        for (int j = 0; j < 8; ++j) v0[j] = bf16s(W[(kb + j) * E_ + tid]);
#pragma unroll
        for (int j = 0; j < 8; ++j) v1[j] = bf16s(W[(kb + 8 + j) * E_ + tid]);
        *(short8*)(wt + tid * E_ + kb)     = v0;
        *(short8*)(wt + tid * E_ + kb + 8) = v1;
    }
}

// ---------------------------------------------------------------------------
// Fused GEMM. Block = 4 phones x 16 batches x TWO sequential 32-col chunks.
// Grid (128,4) = 512 blocks, 2/CU, all-resident (zero generation churn).
// enc (As) + PE (Ps) staged once; chunk-0 stores drain under chunk-1 compute
// (raw lgkm-only barriers after chunk-0's store issue).
__global__ __launch_bounds__(256, 2) void k_fused(
    const float* __restrict__ enc, const short* __restrict__ wt,
    const float* __restrict__ bpos,
    const float* __restrict__ pitch, const int* __restrict__ beats,
    const float* __restrict__ wpitch, const float* __restrict__ bpitch,
    const float* __restrict__ embb,
    const float* __restrict__ W, const int* __restrict__ align,
    const int* __restrict__ text, const int* __restrict__ flags,
    float* __restrict__ out)
{
    __shared__ __align__(16) short As[64 * 256];     // 32KB  enc tile bf16 (persistent)
    __shared__ __align__(16) short Ps[32 * 256];     // 16KB  PE rows bf16 (persistent)
    __shared__ __align__(16) short Bs[32 * 256];     // 16KB  W^T chunk slice
    __shared__ __align__(16) float scratch[64 * 36]; // 9KB   pl (4K) then ew per chunk

    const int tid = threadIdx.x;
    const int i0 = blockIdx.x * 4;                   // phone base
    const int n0base = blockIdx.y * 64;
    const int t0base = i0 * 8;

    // ---- fallback flag (never set for this data) ----
    const bool fb = __any(flags[tid & 31] != 0);
    if (fb) {
        // exact fp32 slow path (never taken). idxl aliases As.
        int (*idxl)[32] = (int(*)[32])As;
        if (tid < 16) {
            int i = 0;
            const int b = tid;
            if (i0 == 0) idxl[b][0] = 0;
            for (int t = 1; t < t0base + 32; ++t) {
                if (align[b * T_ + t] != text[b * S_ + i]) i = min(i + 1, S_ - 1);
                if (t >= t0base) idxl[b][t - t0base] = i;
            }
        }
        __syncthreads();
#pragma unroll
        for (int rr = 0; rr < 2; ++rr) {
            const int r = tid * 2 + rr;              // 0..511 = 16b x 32t
            const int bq = r >> 5, tt = r & 31;
            const int t = t0base + tt;
            const int i = idxl[bq][tt];
            const float* erow = enc + (size_t)(bq * S_ + i) * E_;
            const float p = pitch[(size_t)bq * T_ + t];
            const int bt = beats[(size_t)bq * T_ + t];
            for (int cc = 0; cc < 64; ++cc) {
                const int col = n0base + cc;
                float acc = 0.f;
                for (int k2 = 0; k2 < 128; ++k2) {
                    const float dd = __expf((float)(2 * k2) * NEGC);
                    float s, c;
                    __sincosf((float)t * dd, &s, &c);
                    acc += (erow[2 * k2] + s) * W[(2 * k2) * E_ + col]
                         + (erow[2 * k2 + 1] + c) * W[(2 * k2 + 1) * E_ + col];
                }
                out[((size_t)bq * T_ + t) * E_ + col] =
                    erow[col] + acc + bpos[col] + p * wpitch[col] + bpitch[col]
                    + (bt ? embb[E_ + col] : embb[col]);
            }
        }
        return;
    }

    // ---- stage As = enc rows 0..63 (row r: b = r>>2, phone = i0 + (r&3)) ----
    {
        const int r = tid >> 2, c4 = tid & 3;
        const float* ap = enc + (size_t)((r >> 2) * S_ + i0 + (r & 3)) * E_;
#pragma unroll
        for (int jj = 0; jj < 8; ++jj) {
            const int seg = c4 + 4 * jj;
            float4 f0 = *(const float4*)(ap + seg * 8);
            float4 f1 = *(const float4*)(ap + seg * 8 + 4);
            union { short8 v; unsigned u[4]; } cv;
            cv.u[0] = pk_bf16(f0.x, f0.y);
            cv.u[1] = pk_bf16(f0.z, f0.w);
            cv.u[2] = pk_bf16(f1.x, f1.y);
            cv.u[3] = pk_bf16(f1.z, f1.w);
            *(short8*)&As[(r * 256 + seg * 8) ^ ((r & 7) << 3)] = cv.v;
        }
    }
    // ---- stage Ps = PE rows 0..31 (on-the-fly sincos) ----
    {
        const int r = tid >> 3, c8 = tid & 7;
        const float tf = (float)(t0base + r);
#pragma unroll
        for (int jj = 0; jj < 4; ++jj) {
            const int seg = c8 * 4 + jj;
            union { short8 v; unsigned u[4]; } cv;
#pragma unroll
            for (int m = 0; m < 4; ++m) {
                const int j2 = seg * 4 + m;
                const float d = __expf((float)(2 * j2) * NEGC);
                float s, c;
                __sincosf(tf * d, &s, &c);
                cv.u[m] = pk_bf16(s, c);
            }
            *(short8*)&Ps[(r * 256 + seg * 8) ^ ((r & 7) << 3)] = cv.v;
        }
    }

    const int wid = tid >> 6, lane = tid & 63;
    const int q = lane >> 4, c = lane & 15;
    const int c8q = tid & 7, rgrp = tid >> 3;        // epilogue thread map
    const int j = rgrp & 3;                          // phone offset
    float* const pl = scratch;                       // [4][16][16] patches
    float* const ew = scratch;                       // [64][36] after pl consumed

#pragma unroll
    for (int chunk = 0; chunk < 2; ++chunk) {
        const int n0 = n0base + chunk * 32;

        // ---- stage Bs: wt rows n0..n0+32 (vector, swizzled) ----
        {
            const int r = tid >> 3, cc8 = tid & 7;
            const short* bp = wt + (size_t)(n0 + r) * E_;
#pragma unroll
            for (int jj = 0; jj < 4; ++jj) {
                const int seg = cc8 + 8 * jj;
                short8 v = *(const short8*)(bp + seg * 8);
                *(short8*)&Bs[(r * 256 + seg * 8) ^ ((r & 7) << 3)] = v;
            }
        }
        if (chunk == 0) __syncthreads(); else rawbar();   // staging visible

        // ---- phase 1 MFMA: 32x32 PEW slice, wave (tq, nq) = 16t x 16n ----
        {
            const int tq = wid >> 1, nqp = wid & 1;
            const int ar = tq * 16 + c;
            const int br = nqp * 16 + c;
            f32x4 p = {0.f, 0.f, 0.f, 0.f};
#pragma unroll
            for (int ks = 0; ks < 8; ++ks) {
                const int kidx = ks * 32 + q * 8;
                short8 a = *(const short8*)&Ps[(ar * 256 + kidx) ^ ((ar & 7) << 3)];
                short8 b = *(const short8*)&Bs[(br * 256 + kidx) ^ ((br & 7) << 3)];
                p = __builtin_amdgcn_mfma_f32_16x16x32_bf16(a, b, p, 0, 0, 0);
            }
#pragma unroll
            for (int rr = 0; rr < 4; ++rr)
                pl[(tq * 2 + nqp) * 256 + (q * 4 + rr) * 16 + c] = p[rr];
        }
        if (chunk == 0) __syncthreads(); else rawbar();   // pl visible

        // ---- phase 2 MFMA: wave (mq, nq) = 32 enc-rows x 16 cols ----
        const int mq = wid >> 1, nq = wid & 1;
        const int ra0 = mq * 32 + c, ra1 = ra0 + 16;
        const int rb = nq * 16 + c;
        f32x4 acc0 = {0.f, 0.f, 0.f, 0.f}, acc1 = {0.f, 0.f, 0.f, 0.f};
#pragma unroll
        for (int ks = 0; ks < 8; ++ks) {
            const int kidx = ks * 32 + q * 8;
            short8 a0 = *(const short8*)&As[(ra0 * 256 + kidx) ^ ((ra0 & 7) << 3)];
            short8 a1 = *(const short8*)&As[(ra1 * 256 + kidx) ^ ((ra1 & 7) << 3)];
            short8 b  = *(const short8*)&Bs[(rb * 256 + kidx) ^ ((rb & 7) << 3)];
            acc0 = __builtin_amdgcn_mfma_f32_16x16x32_bf16(a0, b, acc0, 0, 0, 0);
            acc1 = __builtin_amdgcn_mfma_f32_16x16x32_bf16(a1, b, acc1, 0, 0, 0);
        }

        // ---- pv pre-read from pl + uniform epilogue loads ----
        const int gc = n0 + 4 * c8q;
        f32x4 pv[8];
#pragma unroll
        for (int d = 0; d < 8; ++d) {
            const int tl = j * 8 + d;
            pv[d] = *(const f32x4*)&pl[((tl >> 4) * 2 + (c8q >> 2)) * 256
                                       + (tl & 15) * 16 + ((4 * c8q) & 15)];
        }
        const f32x4 wp4 = *(const f32x4*)(wpitch + gc);
        const f32x4 cst = *(const f32x4*)(bpitch + gc) + *(const f32x4*)(bpos + gc);
        const f32x4 be0 = *(const f32x4*)(embb + gc);
        const f32x4 be1 = *(const f32x4*)(embb + E_ + gc);
        if (chunk == 0) __syncthreads(); else rawbar();   // all pl + Bs reads done

        // ---- transpose acc through LDS (D: row = 4q+rr, col = c); stride 36 ----
#pragma unroll
        for (int rr = 0; rr < 4; ++rr) {
            ew[(mq * 32 + q * 4 + rr) * 36 + nq * 16 + c]      = acc0[rr];
            ew[(mq * 32 + 16 + q * 4 + rr) * 36 + nq * 16 + c] = acc1[rr];
        }
        if (chunk == 0) __syncthreads(); else rawbar();   // ew visible

        // ---- epilogue: lane (rgrp, c8q); 2 row-passes x 8 frames; nt stores ----
#pragma unroll
        for (int p = 0; p < 2; ++p) {
            const int row = rgrp + 32 * p;
            const int bq = row >> 2;
            const size_t prow = (size_t)bq * T_ + t0base + j * 8;
            const float4 pi0 = *(const float4*)(pitch + prow);
            const float4 pi1 = *(const float4*)(pitch + prow + 4);
            const int4  bt0 = *(const int4*)(beats + prow);
            const int4  bt1 = *(const int4*)(beats + prow + 4);
            const f32x4 e4  = *(const f32x4*)(enc + (size_t)(bq * S_ + i0 + j) * E_ + gc);
            const f32x4 ewv = *(const f32x4*)&ew[row * 36 + 4 * c8q];
            const f32x4 base = ewv + e4 + cst;
            const float pp[8] = {pi0.x, pi0.y, pi0.z, pi0.w, pi1.x, pi1.y, pi1.z, pi1.w};
            const int   bb[8] = {bt0.x, bt0.y, bt0.z, bt0.w, bt1.x, bt1.y, bt1.z, bt1.w};
#pragma unroll
            for (int d = 0; d < 8; ++d) {
                const f32x4 be = bb[d] ? be1 : be0;
                f32x4 o = base + pv[d] + pp[d] * wp4 + be;
                __builtin_nontemporal_store(o, (f32x4*)(out + (prow + d) * E_ + gc));
            }
        }
        if (chunk == 0) rawbar();   // scratch/Bs free for chunk 1; stores stay in flight
    }
}

// ---------------------------------------------------------------------------
extern "C" void kernel_launch(void* const* d_in, const int* in_sizes, int n_in,
                              void* d_out, int out_size, void* d_ws, size_t ws_size,
                              hipStream_t stream) {
    const float* enc    = (const float*)d_in[0];
    const int*   align  = (const int*)  d_in[1];
    const int*   text   = (const int*)  d_in[2];
    const float* pitch  = (const float*)d_in[3];
    const int*   beats  = (const int*)  d_in[4];
    const float* wpitch = (const float*)d_in[5];
    const float* bpitch = (const float*)d_in[6];
    const float* embb   = (const float*)d_in[7];
    const float* wpos   = (const float*)d_in[8];
    const float* bpos   = (const float*)d_in[9];
    float* out = (float*)d_out;

    char* ws = (char*)d_ws;
    int*   flags = (int*)  (ws + FLAGS_OFF);
    short* wt    = (short*)(ws + WT_OFF);

    hipLaunchKernelGGL(k_prep, dim3(48), dim3(256), 0, stream,
                       align, text, wpos, flags, wt);
    hipLaunchKernelGGL(k_fused, dim3(S_ / 4, 4), dim3(256), 0, stream,
                       enc, wt, bpos, pitch, beats, wpitch, bpitch, embb,
                       wpos, align, text, flags, out);
}

// Round 11
// 22.666 us; speedup vs baseline: 1.1691x; 1.1236x over previous
//
#include <hip/hip_runtime.h>
#include <hip/hip_bf16.h>
#include <math.h>

// Problem constants (fixed by setup_inputs)
constexpr int B_ = 16, S_ = 512, T_ = 4096, E_ = 256;

typedef __attribute__((ext_vector_type(8))) short short8;
typedef __attribute__((ext_vector_type(4))) float f32x4;

// Workspace: 1024 validation flags (2 per fused block), written every call
constexpr size_t FLAGS_OFF = 0;

// -ln(10000)/256
#define NEGC (-0.035977892f)

__device__ __forceinline__ unsigned pk_bf16(float a, float b) {
    __hip_bfloat162 h = __float22bfloat162_rn(make_float2(a, b));
    return *(unsigned*)&h;
}
__device__ __forceinline__ short bf16s(float x) {
    unsigned u = __float_as_uint(x);
    u += 0x7FFFu + ((u >> 16) & 1u);
    return (short)(u >> 16);
}
__device__ __forceinline__ float bf16f(short s) {
    return __uint_as_float(((unsigned)(unsigned short)s) << 16);
}

// Raw barrier: LDS-visibility only — does NOT drain vmcnt, so global stores
// issued before it stay in flight (safe: no cross-wave reads of `out`).
__device__ __forceinline__ void rawbar() {
    asm volatile("s_waitcnt lgkmcnt(0)" ::: "memory");
    __builtin_amdgcn_s_barrier();
    __builtin_amdgcn_sched_barrier(0);
}

// ---------------------------------------------------------------------------
// Fused GEMM, single producer dispatch (R10 core structure).
// Block = 4 phones x 16 batches x two 32-col chunks; grid (128,4); 2/CU.
// Inline: per-block validation slice of the aligner recurrence -> flags.
// Bs staged directly from fp32 W (transpose+cvt in-block; no prep kernel).
// enc folded into ew from LDS (epilogue has no enc re-read).
__global__ __launch_bounds__(256, 2) void k_fused(
    const float* __restrict__ enc, const float* __restrict__ W,
    const float* __restrict__ bpos,
    const float* __restrict__ pitch, const int* __restrict__ beats,
    const float* __restrict__ wpitch, const float* __restrict__ bpitch,
    const float* __restrict__ embb,
    const int* __restrict__ align, const int* __restrict__ text,
    int* __restrict__ flags, float* __restrict__ out)
{
    __shared__ __align__(16) short As[64 * 256];     // 32KB enc tile bf16 (persistent)
    __shared__ __align__(16) short Ps[32 * 256];     // 16KB PE rows bf16 (persistent)
    __shared__ __align__(16) short Bs[32 * 256];     // 16KB W^T chunk slice
    __shared__ __align__(16) float scratch[64 * 36]; // 9KB  pl then ew per chunk

    const int tid = threadIdx.x;
    const int i0 = blockIdx.x * 4;                   // phone base
    const int n0base = blockIdx.y * 64;
    const int t0base = i0 * 8;
    const int v = blockIdx.x * 4 + blockIdx.y;       // 0..511

    // ---- inline validation: disjoint 128-transition slice of the global
    // recurrence induction. All 512 blocks together cover all B*T ids. ----
    if (tid < 128) {
        const int id = v * 128 + tid;
        const int t = id & (T_ - 1), b = id >> 12;
        int bad = 0;
        if (t > 0) {
            const int prev = (t - 1) >> 3;
            const int a = align[id];
            const int expct = (a == text[b * S_ + prev]) ? prev : min(prev + 1, S_ - 1);
            if ((t >> 3) != expct) bad = 1;
        }
        const int anybad = __any(bad) ? 1 : 0;
        if ((tid & 63) == 0) flags[v * 2 + (tid >> 6)] = anybad;  // unconditional
    }

    // ---- stage As = enc rows 0..63 (row r: b = r>>2, phone = i0 + (r&3)) ----
    {
        const int r = tid >> 2, c4 = tid & 3;
        const float* ap = enc + (size_t)((r >> 2) * S_ + i0 + (r & 3)) * E_;
#pragma unroll
        for (int jj = 0; jj < 8; ++jj) {
            const int seg = c4 + 4 * jj;
            float4 f0 = *(const float4*)(ap + seg * 8);
            float4 f1 = *(const float4*)(ap + seg * 8 + 4);
            union { short8 v8; unsigned u[4]; } cv;
            cv.u[0] = pk_bf16(f0.x, f0.y);
            cv.u[1] = pk_bf16(f0.z, f0.w);
            cv.u[2] = pk_bf16(f1.x, f1.y);
            cv.u[3] = pk_bf16(f1.z, f1.w);
            *(short8*)&As[(r * 256 + seg * 8) ^ ((r & 7) << 3)] = cv.v8;
        }
    }
    // ---- stage Ps = PE rows 0..31 (on-the-fly sincos) ----
    {
        const int r = tid >> 3, c8 = tid & 7;
        const float tf = (float)(t0base + r);
#pragma unroll
        for (int jj = 0; jj < 4; ++jj) {
            const int seg = c8 * 4 + jj;
            union { short8 v8; unsigned u[4]; } cv;
#pragma unroll
            for (int m = 0; m < 4; ++m) {
                const int j2 = seg * 4 + m;
                const float d = __expf((float)(2 * j2) * NEGC);
                float s, c;
                __sincosf(tf * d, &s, &c);
                cv.u[m] = pk_bf16(s, c);
            }
            *(short8*)&Ps[(r * 256 + seg * 8) ^ ((r & 7) << 3)] = cv.v8;
        }
    }

    const int wid = tid >> 6, lane = tid & 63;
    const int q = lane >> 4, c = lane & 15;
    const int c8q = tid & 7, rgrp = tid >> 3;        // epilogue thread map
    const int j = rgrp & 3;                          // phone offset
    float* const pl = scratch;                       // [4][16][16] patches
    float* const ew = scratch;                       // [64][36] after pl consumed

#pragma unroll
    for (int chunk = 0; chunk < 2; ++chunk) {
        const int n0 = n0base + chunk * 32;

        // ---- stage Bs from fp32 W: transpose + cvt in-block ----
        // pass: 8 lanes share k-row, read 128B coalesced; write b16 transposed.
        {
            const int kk = tid >> 3;                 // 0..31 (k offset within pass)
            const int nn = (tid & 7) * 4;            // relative n (0..28)
#pragma unroll
            for (int p = 0; p < 8; ++p) {
                const int k = p * 32 + kk;
                const float4 w4 = *(const float4*)(W + (size_t)k * E_ + n0 + nn);
                const short b0 = bf16s(w4.x), b1 = bf16s(w4.y);
                const short b2 = bf16s(w4.z), b3 = bf16s(w4.w);
                Bs[((nn + 0) * 256 + k) ^ (((nn + 0) & 7) << 3)] = b0;
                Bs[((nn + 1) * 256 + k) ^ (((nn + 1) & 7) << 3)] = b1;
                Bs[((nn + 2) * 256 + k) ^ (((nn + 2) & 7) << 3)] = b2;
                Bs[((nn + 3) * 256 + k) ^ (((nn + 3) & 7) << 3)] = b3;
            }
        }
        if (chunk == 0) __syncthreads(); else rawbar();   // staging visible

        // ---- phase 1 MFMA: 32x32 PEW slice, wave (tq, nq) = 16t x 16n ----
        {
            const int tq = wid >> 1, nqp = wid & 1;
            const int ar = tq * 16 + c;
            const int br = nqp * 16 + c;
            f32x4 p = {0.f, 0.f, 0.f, 0.f};
#pragma unroll
            for (int ks = 0; ks < 8; ++ks) {
                const int kidx = ks * 32 + q * 8;
                short8 a = *(const short8*)&Ps[(ar * 256 + kidx) ^ ((ar & 7) << 3)];
                short8 b = *(const short8*)&Bs[(br * 256 + kidx) ^ ((br & 7) << 3)];
                p = __builtin_amdgcn_mfma_f32_16x16x32_bf16(a, b, p, 0, 0, 0);
            }
#pragma unroll
            for (int rr = 0; rr < 4; ++rr)
                pl[(tq * 2 + nqp) * 256 + (q * 4 + rr) * 16 + c] = p[rr];
        }
        if (chunk == 0) __syncthreads(); else rawbar();   // pl visible

        // ---- phase 2 MFMA: wave (mq, nq) = 32 enc-rows x 16 cols ----
        const int mq = wid >> 1, nq = wid & 1;
        const int ra0 = mq * 32 + c, ra1 = ra0 + 16;
        const int rb = nq * 16 + c;
        f32x4 acc0 = {0.f, 0.f, 0.f, 0.f}, acc1 = {0.f, 0.f, 0.f, 0.f};
#pragma unroll
        for (int ks = 0; ks < 8; ++ks) {
            const int kidx = ks * 32 + q * 8;
            short8 a0 = *(const short8*)&As[(ra0 * 256 + kidx) ^ ((ra0 & 7) << 3)];
            short8 a1 = *(const short8*)&As[(ra1 * 256 + kidx) ^ ((ra1 & 7) << 3)];
            short8 b  = *(const short8*)&Bs[(rb * 256 + kidx) ^ ((rb & 7) << 3)];
            acc0 = __builtin_amdgcn_mfma_f32_16x16x32_bf16(a0, b, acc0, 0, 0, 0);
            acc1 = __builtin_amdgcn_mfma_f32_16x16x32_bf16(a1, b, acc1, 0, 0, 0);
        }

        // ---- fold enc into acc (read back from As; saves epilogue e4 loads) ----
        {
            const int gc2 = n0 + nq * 16 + c;        // absolute output col = As k-index
#pragma unroll
            for (int rr = 0; rr < 4; ++rr) {
                const int r0 = mq * 32 + q * 4 + rr, r1 = r0 + 16;
                acc0[rr] += bf16f(As[(r0 * 256 + gc2) ^ ((r0 & 7) << 3)]);
                acc1[rr] += bf16f(As[(r1 * 256 + gc2) ^ ((r1 & 7) << 3)]);
            }
        }

        // ---- pv pre-read from pl + uniform epilogue loads ----
        const int gc = n0 + 4 * c8q;
        f32x4 pv[8];
#pragma unroll
        for (int d = 0; d < 8; ++d) {
            const int tl = j * 8 + d;
            pv[d] = *(const f32x4*)&pl[((tl >> 4) * 2 + (c8q >> 2)) * 256
                                       + (tl & 15) * 16 + ((4 * c8q) & 15)];
        }
        const f32x4 wp4 = *(const f32x4*)(wpitch + gc);
        const f32x4 cst = *(const f32x4*)(bpitch + gc) + *(const f32x4*)(bpos + gc);
        const f32x4 be0 = *(const f32x4*)(embb + gc);
        const f32x4 be1 = *(const f32x4*)(embb + E_ + gc);
        if (chunk == 0) __syncthreads(); else rawbar();   // all pl + Bs reads done

        // ---- transpose acc through LDS (D: row = 4q+rr, col = c); stride 36 ----
#pragma unroll
        for (int rr = 0; rr < 4; ++rr) {
            ew[(mq * 32 + q * 4 + rr) * 36 + nq * 16 + c]      = acc0[rr];
            ew[(mq * 32 + 16 + q * 4 + rr) * 36 + nq * 16 + c] = acc1[rr];
        }
        if (chunk == 0) __syncthreads(); else rawbar();   // ew visible

        // ---- epilogue: lane (rgrp, c8q); 2 row-passes x 8 frames; nt stores ----
#pragma unroll
        for (int p = 0; p < 2; ++p) {
            const int row = rgrp + 32 * p;
            const int bq = row >> 2;
            const size_t prow = (size_t)bq * T_ + t0base + j * 8;
            const float4 pi0 = *(const float4*)(pitch + prow);
            const float4 pi1 = *(const float4*)(pitch + prow + 4);
            const int4  bt0 = *(const int4*)(beats + prow);
            const int4  bt1 = *(const int4*)(beats + prow + 4);
            const f32x4 ewv = *(const f32x4*)&ew[row * 36 + 4 * c8q];
            const f32x4 base = ewv + cst;
            const float pp[8] = {pi0.x, pi0.y, pi0.z, pi0.w, pi1.x, pi1.y, pi1.z, pi1.w};
            const int   bb[8] = {bt0.x, bt0.y, bt0.z, bt0.w, bt1.x, bt1.y, bt1.z, bt1.w};
#pragma unroll
            for (int d = 0; d < 8; ++d) {
                const f32x4 be = bb[d] ? be1 : be0;
                f32x4 o = base + pv[d] + pp[d] * wp4 + be;
                __builtin_nontemporal_store(o, (f32x4*)(out + (prow + d) * E_ + gc));
            }
        }
        if (chunk == 0) rawbar();   // scratch/Bs free for chunk 1; stores in flight
    }
}

// ---------------------------------------------------------------------------
// Fixup: reads the 1024 flags written by k_fused. Clean (always, for this
// data): instant exit. Dirty: fp32-exact full recompute of out.
__global__ __launch_bounds__(256) void k_fixup(
    const float* __restrict__ enc, const int* __restrict__ align,
    const int* __restrict__ text, const float* __restrict__ pitch,
    const int* __restrict__ beats, const float* __restrict__ wpitch,
    const float* __restrict__ bpitch, const float* __restrict__ embb,
    const float* __restrict__ W, const float* __restrict__ bpos,
    const int* __restrict__ flags, float* __restrict__ out)
{
    __shared__ int s[4];
    __shared__ int idxl[256];
    const int tid = threadIdx.x;
    {
        const int4 f = ((const int4*)flags)[tid];    // 256 x int4 = 1024 flags
        const int o = f.x | f.y | f.z | f.w;
        const bool any = __any(o != 0);
        if ((tid & 63) == 0) s[tid >> 6] = any ? 1 : 0;
    }
    __syncthreads();
    if (!(s[0] | s[1] | s[2] | s[3])) return;

    // ---- dirty path (never for this data): exact fp32 recompute ----
    const int b = blockIdx.x >> 4;
    const int tseg = (blockIdx.x & 15) * 256;
    if (tid == 0) {
        int i = 0;
        if (tseg == 0) idxl[0] = 0;
        for (int t = 1; t < tseg + 256; ++t) {
            if (align[b * T_ + t] != text[b * S_ + i]) i = min(i + 1, S_ - 1);
            if (t >= tseg) idxl[t - tseg] = i;
        }
    }
    __syncthreads();
    const int col = tid;
    for (int tt = 0; tt < 256; ++tt) {
        const int t = tseg + tt;
        const int i = idxl[tt];
        const float* erow = enc + (size_t)(b * S_ + i) * E_;
        float acc = 0.f;
        for (int k2 = 0; k2 < 128; ++k2) {
            const float d = __expf((float)(2 * k2) * NEGC);
            float sn, cs;
            __sincosf((float)t * d, &sn, &cs);
            acc += (erow[2 * k2] + sn) * W[(2 * k2) * E_ + col]
                 + (erow[2 * k2 + 1] + cs) * W[(2 * k2 + 1) * E_ + col];
        }
        const float p = pitch[(size_t)b * T_ + t];
        const float be = beats[(size_t)b * T_ + t] ? embb[E_ + col] : embb[col];
        out[((size_t)b * T_ + t) * E_ + col] =
            erow[col] + acc + bpos[col] + p * wpitch[col] + bpitch[col] + be;
    }
}

// ---------------------------------------------------------------------------
extern "C" void kernel_launch(void* const* d_in, const int* in_sizes, int n_in,
                              void* d_out, int out_size, void* d_ws, size_t ws_size,
                              hipStream_t stream) {
    const float* enc    = (const float*)d_in[0];
    const int*   align  = (const int*)  d_in[1];
    const int*   text   = (const int*)  d_in[2];
    const float* pitch  = (const float*)d_in[3];
    const int*   beats  = (const int*)  d_in[4];
    const float* wpitch = (const float*)d_in[5];
    const float* bpitch = (const float*)d_in[6];
    const float* embb   = (const float*)d_in[7];
    const float* wpos   = (const float*)d_in[8];
    const float* bpos   = (const float*)d_in[9];
    float* out = (float*)d_out;

    int* flags = (int*)((char*)d_ws + FLAGS_OFF);

    hipLaunchKernelGGL(k_fused, dim3(S_ / 4, 4), dim3(256), 0, stream,
                       enc, wpos, bpos, pitch, beats, wpitch, bpitch, embb,
                       align, text, flags, out);
    hipLaunchKernelGGL(k_fixup, dim3(256), dim3(256), 0, stream,
                       enc, align, text, pitch, beats, wpitch, bpitch, embb,
                       wpos, bpos, flags, out);
}